// Round 11
// baseline (9158.822 us; speedup 1.0000x reference)
//
#include <hip/hip_runtime.h>

// PositionCloser round 24: half the gates on MFMA, half on FULL-RATE f32 FMA
// in the MFMA cadence gaps. Unifying model from R15/R21/R22 (schedule-
// invariant 1030 cyc/step) + R14/R18/R20 cross-checks: a SINGLE wave issues
// MFMAs at ~32-cyc cadence (16-cyc figure is multi-wave throughput;
// MfmaUtil 49% = 16/32 exact). The step IS the 32-MFMA train = 1024 cyc.
// Fix: i,f stay on MFMA (16 instr = 512-cyc train, R18-verified tiles 0..7);
// g,o move to scalar v_fma_f32 (full-rate, m07) with h broadcast via
// v_readlane SGPRs: 64 readlane + 128 fma = 384 VALU-cyc pinned into the 16
// inter-MFMA gaps by sched_barrier regions (R22: SB pinning works, zero
// cost). Region = {1 MFMA, 4 readlane, 8 fma} ~28 issue-cyc <= 32 gap.
// g,o weights f32 (128 VGPRs; ~250 total - WRITE_SIZE spill tripwire).
// i-extract in the region-8 gap (frees t0-t3). Shell/sync/loss = R15.
// Falsifiable: step ~720 if VALU issues in cadence gaps; ~1080 if the wave
// hard-stalls between MFMAs (refines the cadence model either way).

#define CH  128
#define HID 64

typedef __fp16 half8 __attribute__((ext_vector_type(8)));
typedef float  f32x4 __attribute__((ext_vector_type(4)));
typedef int    int4v __attribute__((ext_vector_type(4)));

#define SB() __builtin_amdgcn_sched_barrier(0)
#define MFMA16(A, B, C) __builtin_amdgcn_mfma_f32_16x16x32_f16((A), (B), (C), 0, 0, 0)

__device__ __forceinline__ float rlf(float v, int l) {
  return __builtin_bit_cast(float, __builtin_amdgcn_readlane(__builtin_bit_cast(int, v), l));
}
__device__ __forceinline__ int packh(float a, float b) {
  return __builtin_bit_cast(int, __builtin_amdgcn_cvt_pkrtz(a, b));
}
__device__ __forceinline__ float frcp(float x) { return __builtin_amdgcn_rcpf(x); }
__device__ __forceinline__ float sigm(float x) { return frcp(1.0f + __expf(-x)); }
__device__ __forceinline__ float tanh_(float x) {
  float e = __expf(2.0f * x);
  return 1.0f - 2.0f * frcp(e + 1.0f);
}
template <int CTRL, int RMASK>
__device__ __forceinline__ float dpp_add(float v) {
  int x = __builtin_amdgcn_update_dpp(0, __builtin_bit_cast(int, v), CTRL, RMASK, 0xF, true);
  return v + __builtin_bit_cast(float, x);
}
__device__ __forceinline__ float dpp_xor1(float v) {  // quad_perm [1,0,3,2]
  int x = __builtin_amdgcn_update_dpp(0, __builtin_bit_cast(int, v), 0xB1, 0xF, 0xF, true);
  return __builtin_bit_cast(float, x);
}
__device__ __forceinline__ float dpp_wave_sum(float v) {  // total lands in lane 63
  v = dpp_add<0x111, 0xF>(v);
  v = dpp_add<0x112, 0xF>(v);
  v = dpp_add<0x114, 0xF>(v);
  v = dpp_add<0x118, 0xF>(v);
  v = dpp_add<0x142, 0xA>(v);   // row_bcast:15
  v = dpp_add<0x143, 0xC>(v);   // row_bcast:31
  return v;
}

__global__ __attribute__((amdgpu_flat_work_group_size(128, 128), amdgpu_waves_per_eu(2, 2)))
void pc_lstm_kernel(const int* __restrict__ inds,
                    const float* __restrict__ p,
                    const float* __restrict__ ls_probs,
                    const float* __restrict__ open_probs,
                    const int* __restrict__ open_slices,
                    const float* __restrict__ open_hx,
                    const float* __restrict__ W_ih,
                    const float* __restrict__ W_hh,
                    const float* __restrict__ b_ih,
                    const float* __restrict__ b_hh,
                    const float* __restrict__ W_out,
                    const float* __restrict__ b_out,
                    const int* __restrict__ n_chunks_p,
                    float* __restrict__ out)
{
  __shared__ __fp16 ring[2][CH][HID];   // 32 KB: h history for the lagged loss
  __shared__ int prod;                  // chunks fully written by wave0
  __shared__ int cons;                  // chunks fully consumed by wave1

  const int tid  = threadIdx.x;
  const int wv   = tid >> 6;           // 0 = compute, 1 = loss
  const int lane = tid & 63;
  const int s    = blockIdx.x;         // one sequence per block
  const int n_chunks = n_chunks_p[0];
  const int tbase = inds[s >> 4] + (s & 15);
  const float2* p2 = (const float2*)p;

  if (tid == 0) { prod = 0; cons = 0; }
  __syncthreads();                      // only barrier in the kernel

  if (wv == 0) {
    // ================= compute wave =================
    const int kg = lane >> 4;          // k-group (A/B fragment k-chunk index)
    const int cc = lane & 15;          // column within a 16-wide N-tile

    // MFMA B fragments for gates i,f (tiles 0..7; R18-verified packing):
    // tile t covers preact rows n = 16t + col; k = 32*kc + 8*kg + j.
    half8 Wb[16];
#pragma unroll
    for (int t = 0; t < 8; ++t) {
#pragma unroll
      for (int kc = 0; kc < 2; ++kc) {
        const float* wp = W_hh + (16 * t + cc) * HID + 32 * kc + 8 * kg;
        half8 w;
#pragma unroll
        for (int j = 0; j < 8; ++j) w[j] = (__fp16)wp[j];
        Wb[2 * t + kc] = w;
      }
    }

    // f32 weights for gates g,o: lane owns rows hid=lane (128 VGPRs).
    float Wg[64], Wo[64];
    {
      const float4* rg = (const float4*)(W_hh + (2 * HID + lane) * HID);
      const float4* ro = (const float4*)(W_hh + (3 * HID + lane) * HID);
#pragma unroll
      for (int j = 0; j < 16; ++j) {
        const float4 vg = rg[j], vo = ro[j];
        Wg[4 * j] = vg.x; Wg[4 * j + 1] = vg.y; Wg[4 * j + 2] = vg.z; Wg[4 * j + 3] = vg.w;
        Wo[4 * j] = vo.x; Wo[4 * j + 1] = vo.y; Wo[4 * j + 2] = vo.z; Wo[4 * j + 3] = vo.w;
      }
    }

    float wxa[4], wxb[4], bb[4];
#pragma unroll
    for (int g = 0; g < 4; ++g) {
      const int r = g * HID + lane;
      wxa[g] = W_ih[2 * r];
      wxb[g] = W_ih[2 * r + 1];
      bb[g]  = b_ih[r] + b_hh[r];
    }
    float h = open_hx[(s * 2 + 0) * HID + lane];
    float c = open_hx[(s * 2 + 1) * HID + lane];

    // bpermute byte-indices (loop-invariant):
    // a0 word w pulls hp from lane 8*kg+2w; a1 from lane 32+8*kg+2w.
    int ia0[4], ia1[4];
#pragma unroll
    for (int w = 0; w < 4; ++w) {
      ia0[w] = 4 * (8 * kg + 2 * w);
      ia1[w] = 4 * (32 + 8 * kg + 2 * w);
    }

    const bool u1 = (lane & 16) != 0;  // bit0 of u = lane>>4
    const bool u2 = (lane & 32) != 0;  // bit1 of u
    const f32x4 zero4 = {0.f, 0.f, 0.f, 0.f};

    float2 curA = p2[tbase + lane];
    float2 curB = p2[tbase + HID + lane];
    float2 nxtA = curA, nxtB = curB;

// one cadence-gap group: 4 h broadcasts + 8 full-rate f32 FMAs (2 chains/gate)
#define GO4(R) { \
    const float s0_ = rlf(h, 4 * (R) + 0), s1_ = rlf(h, 4 * (R) + 1); \
    const float s2_ = rlf(h, 4 * (R) + 2), s3_ = rlf(h, 4 * (R) + 3); \
    ga = fmaf(s0_, Wg[4 * (R) + 0], ga);  oa = fmaf(s0_, Wo[4 * (R) + 0], oa); \
    gb = fmaf(s1_, Wg[4 * (R) + 1], gb);  ob = fmaf(s1_, Wo[4 * (R) + 1], ob); \
    ga = fmaf(s2_, Wg[4 * (R) + 2], ga);  oa = fmaf(s2_, Wo[4 * (R) + 2], oa); \
    gb = fmaf(s3_, Wg[4 * (R) + 3], gb);  ob = fmaf(s3_, Wo[4 * (R) + 3], ob); } SB()

    for (int off = 0; off < n_chunks; ++off) {
      if (off) { curA = nxtA; curB = nxtB; }
      const float px0 = rlf(curA.x, 0);
      const float px1 = rlf(curA.y, 0);
      float2 xA, xB;                       // pre-subtracted chunk base
      xA.x = curA.x - px0; xA.y = curA.y - px1;
      xB.x = curB.x - px0; xB.y = curB.y - px1;
      if (off + 1 < n_chunks) {
        const int nb = tbase + (off + 1) * CH;
        nxtA = p2[nb + lane];
        nxtB = p2[nb + HID + lane];
      }
      while (__hip_atomic_load(&cons, __ATOMIC_ACQUIRE, __HIP_MEMORY_SCOPE_WORKGROUP) + 2 <= off)
        __builtin_amdgcn_s_sleep(8);

      __fp16* slot = &ring[off & 1][0][0];
#pragma unroll
      for (int hf = 0; hf < 2; ++hf) {
        const float xcx = hf ? xB.x : xA.x;
        const float xcy = hf ? xB.y : xA.y;
#pragma unroll 1
        for (int tl = 0; tl < 64; ++tl) {
          // ---- head: packed h pairs -> 8 bperm; x scalars; g,o seeds ----
          const int hp = packh(h, dpp_xor1(h));   // even lane 2j: (h_2j, h_2j+1)
          int4v A0, A1;
#pragma unroll
          for (int w = 0; w < 4; ++w) A0[w] = __builtin_amdgcn_ds_bpermute(ia0[w], hp);
#pragma unroll
          for (int w = 0; w < 4; ++w) A1[w] = __builtin_amdgcn_ds_bpermute(ia1[w], hp);
          const half8 a0 = __builtin_bit_cast(half8, A0);   // k = 0..31
          const half8 a1 = __builtin_bit_cast(half8, A1);   // k = 32..63
          const float x0 = rlf(xcx, tl);
          const float x1 = rlf(xcy, tl);

          float ga = fmaf(x0, wxa[2], bb[2]);
          float gb = x1 * wxb[2];
          float oa = fmaf(x0, wxa[3], bb[3]);
          float ob = x1 * wxb[3];
          float ei = 0.0f;
          SB();

          // ---- 16 cadence regions: 1 MFMA + GO4 each ----
          f32x4 t0 = MFMA16(a0, Wb[0],  zero4); GO4(0);
          t0       = MFMA16(a1, Wb[1],  t0);    GO4(1);
          f32x4 t1 = MFMA16(a0, Wb[2],  zero4); GO4(2);
          t1       = MFMA16(a1, Wb[3],  t1);    GO4(3);
          f32x4 t2 = MFMA16(a0, Wb[4],  zero4); GO4(4);
          t2       = MFMA16(a1, Wb[5],  t2);    GO4(5);
          f32x4 t3 = MFMA16(a0, Wb[6],  zero4); GO4(6);
          t3       = MFMA16(a1, Wb[7],  t3);    GO4(7);

          f32x4 t4 = MFMA16(a0, Wb[8],  zero4);
          // region 8 gap: i-extract (t0..t3 completed ~4 regions ago) + 2 pairs
          {
            const float si01 = u1 ? t1[0] : t0[0];
            const float si23 = u1 ? t3[0] : t2[0];
            const float di   = u2 ? si23 : si01;
            const float pai  = fmaf(x0, wxa[0], fmaf(x1, wxb[0], di + bb[0]));
            ei = __expf(-pai);
            const float s0_ = rlf(h, 32), s1_ = rlf(h, 33);
            ga = fmaf(s0_, Wg[32], ga);  oa = fmaf(s0_, Wo[32], oa);
            gb = fmaf(s1_, Wg[33], gb);  ob = fmaf(s1_, Wo[33], ob);
          }
          SB();
          t4 = MFMA16(a1, Wb[9], t4);
          // region 9 gap: finish j=34..39
          {
            const float s0_ = rlf(h, 34), s1_ = rlf(h, 35);
            const float s2_ = rlf(h, 36), s3_ = rlf(h, 37);
            ga = fmaf(s0_, Wg[34], ga);  oa = fmaf(s0_, Wo[34], oa);
            gb = fmaf(s1_, Wg[35], gb);  ob = fmaf(s1_, Wo[35], ob);
            ga = fmaf(s2_, Wg[36], ga);  oa = fmaf(s2_, Wo[36], oa);
            gb = fmaf(s3_, Wg[37], gb);  ob = fmaf(s3_, Wo[37], ob);
          }
          SB();
          f32x4 t5 = MFMA16(a0, Wb[10], zero4);
          {
            const float s0_ = rlf(h, 38), s1_ = rlf(h, 39);
            ga = fmaf(s0_, Wg[38], ga);  oa = fmaf(s0_, Wo[38], oa);
            gb = fmaf(s1_, Wg[39], gb);  ob = fmaf(s1_, Wo[39], ob);
          }
          SB();
          t5 = MFMA16(a1, Wb[11], t5);    GO4(10);
          f32x4 t6 = MFMA16(a0, Wb[12], zero4); GO4(11);
          t6 = MFMA16(a1, Wb[13], t6);    GO4(12);
          f32x4 t7 = MFMA16(a0, Wb[14], zero4); GO4(13);
          t7 = MFMA16(a1, Wb[15], t7);    GO4(14);
          GO4(15);

          // ---- tail: g,o finish; f-extract; gates; c; tanh; h ----
          const float eg   = __expf(2.0f * (ga + gb));
          const float og   = sigm(oa + ob);
          const float sf01 = u1 ? t5[0] : t4[0];
          const float sf23 = u1 ? t7[0] : t6[0];
          const float df   = u2 ? sf23 : sf01;
          const float paf  = fmaf(x0, wxa[1], fmaf(x1, wxb[1], df + bb[1]));
          const float fg   = sigm(paf);
          const float ig   = frcp(1.0f + ei);
          const float gg   = 1.0f - 2.0f * frcp(eg + 1.0f);
          c = fmaf(fg, c, ig * gg);
          h = og * tanh_(c);

          const int tt = hf * 64 + tl;
          slot[tt * HID + lane] = (__fp16)h;   // ds_write_b16 (ring, off chain)
        }
      }
      if (lane == 0)
        __hip_atomic_store(&prod, off + 1, __ATOMIC_RELEASE, __HIP_MEMORY_SCOPE_WORKGROUP);
    }
#undef GO4
  } else {
    // ================= loss wave =================
    const float wo   = W_out[lane];
    const float bout = b_out[0];
    const int   os   = open_slices[s];
    const float OL   = __logf(p[2 * os]) + __logf(p[2 * os + 1]);
    const float coef = open_probs[s] * (2.0f * ls_probs[s] - 1.0f);

    float S = 1.0f, D = 1.0f, lsum = 0.0f, psum = 0.0f;

    for (int off = 0; off < n_chunks; ++off) {
      const int cb = tbase + off * CH;
      const float2 cA = p2[cb + lane];
      const float2 cB = p2[cb + HID + lane];
      const float LA = __logf(cA.x) + __logf(cA.y);
      const float LB = __logf(cB.x) + __logf(cB.y);

      while (__hip_atomic_load(&prod, __ATOMIC_ACQUIRE, __HIP_MEMORY_SCOPE_WORKGROUP) <= off)
        __builtin_amdgcn_s_sleep(32);

      const __fp16* slot = &ring[off & 1][0][0];
#pragma unroll 1
      for (int tt = 0; tt < CH; ++tt) {
        const float hv = (float)slot[tt * HID + lane];
        const float z  = rlf(dpp_wave_sum(hv * wo), 63);
        const float pr = sigm(z + bout);
        const float Lt = (tt < 64) ? rlf(LA, tt) : rlf(LB, tt - 64);
        const float pn = (tt == 0) ? pr : pr * D;
        lsum = fmaf(pn, Lt, lsum);
        psum += pn;
        if (tt == 0)           D = S * (1.0f - pr);   // chunk t=0 undiscounted (ref quirk)
        else if (tt < CH - 1)  D *= (1.0f - pr);
        else                   S = D;                  // carry excludes (1-p_last)
      }
      if (lane == 0)
        __hip_atomic_store(&cons, off + 1, __ATOMIC_RELEASE, __HIP_MEMORY_SCOPE_WORKGROUP);
    }
    if (lane == 0) atomicAdd(out, coef * (lsum - OL * psum));
  }
}

extern "C" void kernel_launch(void* const* d_in, const int* in_sizes, int n_in,
                              void* d_out, int out_size, void* d_ws, size_t ws_size,
                              hipStream_t stream) {
  (void)hipMemsetAsync(d_out, 0, sizeof(float), stream);

  pc_lstm_kernel<<<dim3(1024), dim3(128), 0, stream>>>(
      (const int*)d_in[0],    // inds
      (const float*)d_in[1],  // p
      (const float*)d_in[2],  // ls_probs
      (const float*)d_in[3],  // open_probs
      (const int*)d_in[4],    // open_slices
      (const float*)d_in[5],  // open_hx
      (const float*)d_in[6],  // W_ih
      (const float*)d_in[7],  // W_hh
      (const float*)d_in[8],  // b_ih
      (const float*)d_in[9],  // b_hh
      (const float*)d_in[10], // W_out
      (const float*)d_in[11], // b_out
      (const int*)d_in[12],   // n_chunks
      (float*)d_out);
}